// Round 1
// 1392.330 us; speedup vs baseline: 1.6522x; 1.6522x over previous
//
#include <hip/hip_runtime.h>

// Problem constants (B, H, W) from the reference.
#define BB 8
#define HH 1080
#define WW 1920
constexpr int HWc  = HH * WW;          // 2,073,600
constexpr int Ntot = BB * HWc;         // 16,588,800

constexpr int TILE = 64;               // OUTPUT core side (exclusive per block)
constexpr int MAR  = 32;               // gather margin: P(|N(0,10)| > 32) ~ 1.4e-3 per tail
constexpr int REG  = TILE + 2 * MAR;   // 128 -> source region 128x128
constexpr int WT   = WW / TILE;        // 30 (exact)
constexpr int HT   = (HH + TILE - 1) / TILE;  // 17 (last core partial: rows 1024..1079)
constexpr int NTILE = WT * HT;         // 510 tiles per image
constexpr int CELLS = TILE * TILE;     // 4096 cells per channel plane

static_assert(TILE == 64, "ownership test uses >>6");

// Workspace: 3 planar channels {sum(-fx*w), sum(-fy*w), sum(w)}, each Ntot floats
// (199 MB total; proven available in a previous session).

// ---------------------------------------------------------------------------
// Pre-pass: the RARE corners whose SOURCE lies outside the gather region of the
// corner's OWNER tile (|flow| beyond margin). Global atomics into acc, BEFORE
// tile_k, so they never race with tile_k's exclusive non-atomic writeback.
// Predicate mirrors tile_k exactly (integer arithmetic):
//   tile_k covers corner (cx,cy) iff source (x,y) is inside
//   [ (cx/64)*64-32, +128 ) x [ (cy/64)*64-32, +128 ).
// ---------------------------------------------------------------------------
__global__ __launch_bounds__(256) void prepass_k(const float* __restrict__ flow,
                                                 const float* __restrict__ depth,
                                                 float* __restrict__ acc) {
    int idx = blockIdx.x * 256 + threadIdx.x;
    if (idx >= Ntot) return;
    int b = idx / HWc;
    int p = idx - b * HWc;
    int y = p / WW;
    int x = p - y * WW;

    const size_t fbase = (size_t)b * 2 * HWc;
    float fx = flow[fbase + p];
    float fy = flow[fbase + HWc + p];
    float x2 = (float)x + fx;
    float y2 = (float)y + fy;
    if (!(x2 >= 0.f && x2 <= (float)(WW - 1) && y2 >= 0.f && y2 <= (float)(HH - 1)))
        return;

    int ixL = min(max((int)floorf(x2), 0), WW - 1);
    int iyT = min(max((int)floorf(y2), 0), HH - 1);
    int ixR = min(ixL + 1, WW - 1);
    int iyB = min(iyT + 1, HH - 1);

    int cxs[2] = {ixL, ixR};
    int cys[2] = {iyT, iyB};
    bool anyOut = false;
#pragma unroll
    for (int a = 0; a < 2; ++a)
#pragma unroll
        for (int c = 0; c < 2; ++c) {
            int cx = cxs[c], cy = cys[a];
            int ox = (cx / TILE) * TILE - MAR;
            int oy = (cy / TILE) * TILE - MAR;
            if (!(x >= ox && x < ox + REG && y >= oy && y < oy + REG))
                anyOut = true;
        }
    if (!anyOut) return;   // ~99.97% of threads exit here

    float w = depth[(size_t)b * HWc + p];
    float vx = -fx * w;
    float vy = -fy * w;
    float* a0 = acc + (size_t)b * HWc;
    float* a1 = acc + (size_t)Ntot + (size_t)b * HWc;
    float* a2 = acc + (size_t)2 * Ntot + (size_t)b * HWc;
#pragma unroll
    for (int a = 0; a < 2; ++a)
#pragma unroll
        for (int c = 0; c < 2; ++c) {
            int cx = cxs[c], cy = cys[a];
            int ox = (cx / TILE) * TILE - MAR;
            int oy = (cy / TILE) * TILE - MAR;
            if (!(x >= ox && x < ox + REG && y >= oy && y < oy + REG)) {
                int q = cy * WW + cx;
                atomicAdd(a0 + q, vx);
                atomicAdd(a1 + q, vy);
                atomicAdd(a2 + q, w);
            }
        }
}

// ---------------------------------------------------------------------------
// Gather-tile kernel: one block per EXCLUSIVE 64x64 output core. Reads the
// 128x128 source neighborhood, splats all 3 channels into 48 KB LDS at once,
// then (race-free) merges the prepass contributions from acc, computes the
// average in-place (avg_k fused), writes out + count plane. Single launch,
// no phases. b = blockIdx%8 gives each XCD one image (L2-local regions).
// ---------------------------------------------------------------------------
__global__ __launch_bounds__(256, 3) void tile_k(const float* __restrict__ flow,
                                                 const float* __restrict__ depth,
                                                 float* acc,   // no restrict: plane2 read+write
                                                 float* __restrict__ out) {
    __shared__ float sm[3 * CELLS];    // 48 KB -> 3 blocks/CU
    const int bid  = blockIdx.x;
    const int b    = bid & 7;          // dispatch i -> XCD i%8 -> image i%8
    const int tile = bid >> 3;
    const int ty   = tile / WT;
    const int tx   = tile - ty * WT;
    const int X0 = tx * TILE, Y0 = ty * TILE;
    const int rx0 = X0 - MAR, ry0 = Y0 - MAR;
    const int tid = threadIdx.x;

    // zero LDS (12 x float4 per thread)
    float4* sm4 = (float4*)sm;
#pragma unroll
    for (int k = 0; k < 3 * CELLS / 4 / 256; ++k)
        sm4[k * 256 + tid] = make_float4(0.f, 0.f, 0.f, 0.f);
    __syncthreads();

    const float* fxp = flow + (size_t)b * 2 * HWc;
    const float* fyp = fxp + HWc;
    const float* dp  = depth + (size_t)b * HWc;

    // splat: 64 iterations, 2 region rows per iteration, coalesced loads
    for (int k = 0; k < REG * REG / 256; ++k) {
        int i  = k * 256 + tid;
        int gy = ry0 + (i >> 7);
        int gx = rx0 + (i & 127);
        if ((unsigned)gy < (unsigned)HH && (unsigned)gx < (unsigned)WW) {
            int p = gy * WW + gx;
            float fx = fxp[p], fy = fyp[p];
            float x2 = (float)gx + fx, y2 = (float)gy + fy;
            if (x2 >= 0.f && x2 <= (float)(WW - 1) &&
                y2 >= 0.f && y2 <= (float)(HH - 1)) {
                int ixL = min(max((int)floorf(x2), 0), WW - 1);
                int iyT = min(max((int)floorf(y2), 0), HH - 1);
                int ixR = min(ixL + 1, WW - 1);
                int iyB = min(iyT + 1, HH - 1);
                // early reject: corner bounding box vs this core (exact)
                if (ixR >= X0 && ixL < X0 + TILE && iyB >= Y0 && iyT < Y0 + TILE) {
                    float w  = dp[p];
                    float vx = -fx * w, vy = -fy * w;
                    int cxs[2] = {ixL, ixR};
                    int cys[2] = {iyT, iyB};
#pragma unroll
                    for (int a = 0; a < 2; ++a)
#pragma unroll
                        for (int c = 0; c < 2; ++c) {
                            int cx = cxs[c], cy = cys[a];
                            if ((cx >> 6) == tx && (cy >> 6) == ty) {  // owned here
                                int cell = ((cy - Y0) << 6) + (cx - X0);
                                atomicAdd(&sm[cell],             vx);
                                atomicAdd(&sm[cell + CELLS],     vy);
                                atomicAdd(&sm[cell + 2 * CELLS], w);
                            }
                        }
                }
            }
        }
    }
    __syncthreads();

    // exclusive writeback, fused with average: merge prepass acc, divide,
    // write out (2 planes) + count plane (acc plane 2). float4 throughout.
    const float* a0 = acc + (size_t)b * HWc;
    const float* a1 = acc + (size_t)Ntot + (size_t)b * HWc;
    float*       a2 = acc + (size_t)2 * Ntot + (size_t)b * HWc;
    float* o0 = out + (size_t)b * 2 * HWc;
    float* o1 = o0 + HWc;
#pragma unroll
    for (int k = 0; k < CELLS / 4 / 256; ++k) {        // 4 iterations
        int j  = k * 256 + tid;                        // float4 cell index [0,1024)
        int r  = j >> 4;
        int gy = Y0 + r;
        if (gy < HH) {
            int q = gy * WW + X0 + ((j & 15) << 2);
            float4 vx = sm4[j];
            float4 vy = sm4[j + CELLS / 4];
            float4 wv = sm4[j + 2 * CELLS / 4];
            float4 e0 = *(const float4*)(a0 + q);
            float4 e1 = *(const float4*)(a1 + q);
            float4 e2 = *(const float4*)(a2 + q);
            vx.x += e0.x; vx.y += e0.y; vx.z += e0.z; vx.w += e0.w;
            vy.x += e1.x; vy.y += e1.y; vy.z += e1.z; vy.w += e1.w;
            wv.x += e2.x; wv.y += e2.y; wv.z += e2.z; wv.w += e2.w;
            float i0 = wv.x > 0.f ? 1.f / wv.x : 0.f;
            float i1 = wv.y > 0.f ? 1.f / wv.y : 0.f;
            float i2 = wv.z > 0.f ? 1.f / wv.z : 0.f;
            float i3 = wv.w > 0.f ? 1.f / wv.w : 0.f;
            float4 r0, r1;
            r0.x = vx.x * i0; r0.y = vx.y * i1; r0.z = vx.z * i2; r0.w = vx.w * i3;
            r1.x = vy.x * i0; r1.y = vy.y * i1; r1.z = vy.z * i2; r1.w = vy.w * i3;
            *(float4*)(o0 + q) = r0;
            *(float4*)(o1 + q) = r1;
            *(float4*)(a2 + q) = wv;   // final count for fill_k
        }
    }
}

// ---------------------------------------------------------------------------
// Hole fill: for count==0 pixels, average nearest filled pixel in each of the
// 4 axis directions. Reads only filled pixels, writes only holes.
// ---------------------------------------------------------------------------
__global__ __launch_bounds__(256) void fill_k(float* __restrict__ out,
                                              const float* __restrict__ cw) {
    int idx = blockIdx.x * 256 + threadIdx.x;
    if (idx >= Ntot) return;
    if (cw[idx] > 0.f) return;

    int b = idx / HWc;
    int p = idx - b * HWc;
    int y = p / WW;
    int x = p - y * WW;

    const float* cb = cw + (size_t)b * HWc;
    const float* o0 = out + (size_t)b * 2 * HWc;
    const float* o1 = o0 + HWc;

    float s = 0.f, s0 = 0.f, s1 = 0.f;
    for (int j = x - 1; j >= 0; --j) {
        int q = y * WW + j;
        if (cb[q] > 0.f) { s += 1.f; s0 += o0[q]; s1 += o1[q]; break; }
    }
    for (int j = x + 1; j < WW; ++j) {
        int q = y * WW + j;
        if (cb[q] > 0.f) { s += 1.f; s0 += o0[q]; s1 += o1[q]; break; }
    }
    for (int i = y - 1; i >= 0; --i) {
        int q = i * WW + x;
        if (cb[q] > 0.f) { s += 1.f; s0 += o0[q]; s1 += o1[q]; break; }
    }
    for (int i = y + 1; i < HH; ++i) {
        int q = i * WW + x;
        if (cb[q] > 0.f) { s += 1.f; s0 += o0[q]; s1 += o1[q]; break; }
    }

    if (s > 0.f) {
        ((float*)o0)[p] = s0 / s;
        ((float*)o1)[p] = s1 / s;
    }
}

extern "C" void kernel_launch(void* const* d_in, const int* in_sizes, int n_in,
                              void* d_out, int out_size, void* d_ws, size_t ws_size,
                              hipStream_t stream) {
    const float* flow  = (const float*)d_in[0];   // (B,2,H,W)
    const float* depth = (const float*)d_in[1];   // (B,1,H,W)
    float* out = (float*)d_out;                   // (B,2,H,W)
    float* acc = (float*)d_ws;                    // 3 planes x Ntot floats = 199 MB

    const int threads = 256;
    const int grid1d = (Ntot + threads - 1) / threads;

    // zero the accumulator (graph-capture-safe)
    hipMemsetAsync(acc, 0, (size_t)3 * Ntot * sizeof(float), stream);

    // rare far-flung corners via global atomics (must precede tile_k)
    prepass_k<<<grid1d, threads, 0, stream>>>(flow, depth, acc);

    // single launch: exclusive output tiles, fused splat+merge+average
    tile_k<<<NTILE * BB, threads, 0, stream>>>(flow, depth, acc, out);

    fill_k<<<grid1d, threads, 0, stream>>>(out, acc + (size_t)2 * Ntot);
}